// Round 5
// baseline (375.467 us; speedup 1.0000x reference)
//
#include <hip/hip_runtime.h>

// x_t = a_t * x_{t-1} + u_t ; B=8, T=4096, D=1024, fp32.
// R7: T-tiled 3-pass scan, 2 halves, LLC-locality-ordered.
// History: R2 (src batching), R5 (asm 8-deep reg pipeline), R6 (LDS staging,
// 64KB/CU in flight, counted vmcnt) ALL pinned at ~2.7 TB/s delivered, 50%
// LLC hit (FETCH=134MB for 268MB of reads: a+u=268MB > 256MB LLC, thrash).
// => throughput wall on the read path, paid twice (pass1 + pass3).
// Fix: process T in 2 halves; each half's a,u (134MB) fits LLC. Order
// reduce(h)->scan(h)->apply(h) so apply re-reads from LLC, not HBM. Carry
// state chains the halves' scans. out-stores non-temporal (write-once; don't
// evict the resident half). Kernels are the simple R2 forms.
#define BB 8
#define TT 4096
#define DD 1024
#define SS 128            // total segments along T
#define SSH 64            // segments per half
#define TSEG (TT / SS)    // 32 timesteps per segment
#define STR (DD / 4)      // float4 row stride
#define CH 8              // timesteps per load batch

typedef float natf4 __attribute__((ext_vector_type(4)));

static __device__ __forceinline__ float4 ffma4(const float4 a, const float4 x,
                                               const float4 u) {
  return make_float4(fmaf(a.x, x.x, u.x), fmaf(a.y, x.y, u.y),
                     fmaf(a.z, x.z, u.z), fmaf(a.w, x.w, u.w));
}
static __device__ __forceinline__ float4 fmul4(const float4 a, const float4 b) {
  return make_float4(a.x * b.x, a.y * b.y, a.z * b.z, a.w * b.w);
}
static __device__ __forceinline__ void nt_store4(float4* p, const float4 v) {
  natf4 nv;
  nv.x = v.x; nv.y = v.y; nv.z = v.z; nv.w = v.w;
  __builtin_nontemporal_store(nv, (natf4*)p);
}

// ---------------------------------------------------------------------------
// Pass 1 (per half): per-segment affine summary (A = prod a, U = zero-init
// scan). Block = one (b, s_local); thread = 4 channels. Streams this half's
// a,u from HBM, filling the LLC for pass 3.
// ---------------------------------------------------------------------------
__global__ __launch_bounds__(256) void seg_reduce(
    const float* __restrict__ a, const float* __restrict__ u,
    float* __restrict__ wsA, float* __restrict__ wsU, int s_base) {
  const int b  = blockIdx.x >> 6;       // / SSH
  const int sl = blockIdx.x & (SSH - 1);
  const int d4 = threadIdx.x << 2;

  const size_t base = ((size_t)b * TT + (size_t)(s_base + sl) * TSEG) * DD + d4;
  const float4* __restrict__ ap = (const float4*)(a + base);
  const float4* __restrict__ up = (const float4*)(u + base);

  float4 A = make_float4(1.f, 1.f, 1.f, 1.f);
  float4 U = make_float4(0.f, 0.f, 0.f, 0.f);

#pragma unroll 1
  for (int tb = 0; tb < TSEG; tb += CH) {
    float4 av[CH], uv[CH];
#pragma unroll
    for (int k = 0; k < CH; ++k) {
      av[k] = ap[(size_t)(tb + k) * STR];
      uv[k] = up[(size_t)(tb + k) * STR];
    }
#pragma unroll
    for (int k = 0; k < CH; ++k) {
      U = ffma4(av[k], U, uv[k]);
      A = fmul4(A, av[k]);
    }
  }

  // half-local workspace layout [B][SSH][D]
  const size_t w = ((size_t)b * SSH + sl) * DD + d4;
  *(float4*)(wsA + w) = A;
  *(float4*)(wsU + w) = U;
}

// ---------------------------------------------------------------------------
// Pass 2 (per half): scan across this half's 64 segment summaries.
// Block = 64 channels; 4 waves x 16 segments each. xin = x0 (h0) or the
// previous half's carry (h1). Emits xstart (absolute segment index) and the
// half's carry-out state.
// ---------------------------------------------------------------------------
__global__ __launch_bounds__(256) void seg_scan(
    const float* __restrict__ xin, const float* __restrict__ wsA,
    const float* __restrict__ wsU, float* __restrict__ xstart,
    float* __restrict__ xcarry, int s_base) {
  __shared__ float ldsA[SSH * 64];      // [s][ch] : 16 KiB
  __shared__ float ldsU[SSH * 64];      // 16 KiB
  __shared__ float wsumA[4][64];        // per-wave chunk transform
  __shared__ float wsumU[4][64];

  const int b  = blockIdx.x >> 4;       // 16 channel-groups per b
  const int d0 = (blockIdx.x & 15) << 6;
  const int ch = threadIdx.x & 63;
  const int wv = threadIdx.x >> 6;      // 0..3

  // stage summaries: wave-coalesced (fixed s, 64 consecutive d per instr)
#pragma unroll 4
  for (int it = 0; it < SSH / 4; ++it) {
    const int s = (it << 2) + wv;
    const size_t g = ((size_t)b * SSH + s) * DD + d0 + ch;
    ldsA[s * 64 + ch] = wsA[g];
    ldsU[s * 64 + ch] = wsU[g];
  }
  __syncthreads();

  // wave-chunk compose: segments [16w, 16w+16)
  float Ac = 1.f, Uc = 0.f;
  const int s0 = wv * (SSH / 4);
#pragma unroll 4
  for (int k = 0; k < SSH / 4; ++k) {
    const float As = ldsA[(s0 + k) * 64 + ch];
    const float Us = ldsU[(s0 + k) * 64 + ch];
    Uc = fmaf(As, Uc, Us);
    Ac *= As;
  }
  wsumA[wv][ch] = Ac;
  wsumU[wv][ch] = Uc;
  __syncthreads();

  // entry state for this wave's chunk
  float x = xin[(size_t)b * DD + d0 + ch];
  for (int w2 = 0; w2 < wv; ++w2)
    x = fmaf(wsumA[w2][ch], x, wsumU[w2][ch]);

  // replay: emit state entering each segment (absolute index), then carry
#pragma unroll 4
  for (int k = 0; k < SSH / 4; ++k) {
    const int s = s0 + k;
    xstart[((size_t)b * SS + s_base + s) * DD + d0 + ch] = x;
    x = fmaf(ldsA[s * 64 + ch], x, ldsU[s * 64 + ch]);
  }
  if (wv == 3)                          // state after the half's last segment
    xcarry[(size_t)b * DD + d0 + ch] = x;
}

// ---------------------------------------------------------------------------
// Pass 3 (per half): replay each segment from its entry state. Reads a,u —
// LLC-resident from this half's pass 1. Non-temporal out stores (write-once;
// keep them from evicting the resident half).
// ---------------------------------------------------------------------------
__global__ __launch_bounds__(256) void seg_apply(
    const float* __restrict__ a, const float* __restrict__ u,
    const float* __restrict__ xstart, float* __restrict__ out, int s_base) {
  const int b  = blockIdx.x >> 6;
  const int sl = blockIdx.x & (SSH - 1);
  const int d4 = threadIdx.x << 2;

  const size_t base = ((size_t)b * TT + (size_t)(s_base + sl) * TSEG) * DD + d4;
  const float4* __restrict__ ap = (const float4*)(a + base);
  const float4* __restrict__ up = (const float4*)(u + base);
  float4* __restrict__ op = (float4*)(out + base);

  const size_t w = ((size_t)b * SS + s_base + sl) * DD + d4;
  float4 x = *(const float4*)(xstart + w);

#pragma unroll 1
  for (int tb = 0; tb < TSEG; tb += CH) {
    float4 av[CH], uv[CH];
#pragma unroll
    for (int k = 0; k < CH; ++k) {
      av[k] = ap[(size_t)(tb + k) * STR];
      uv[k] = up[(size_t)(tb + k) * STR];
    }
#pragma unroll
    for (int k = 0; k < CH; ++k) {
      x = ffma4(av[k], x, uv[k]);
      nt_store4(op + (size_t)(tb + k) * STR, x);
    }
  }
}

extern "C" void kernel_launch(void* const* d_in, const int* in_sizes, int n_in,
                              void* d_out, int out_size, void* d_ws, size_t ws_size,
                              hipStream_t stream) {
  const float* x0 = (const float*)d_in[0];  // [B, D]
  const float* a  = (const float*)d_in[1];  // [B, T, D]
  const float* u  = (const float*)d_in[2];  // [B, T, D]
  float* out = (float*)d_out;               // [B, T, D]

  const size_t half_elems = (size_t)BB * SSH * DD;  // 2 MiB of floats
  float* wsA    = (float*)d_ws;                     // [B][SSH][D] (per-half)
  float* wsU    = wsA + half_elems;                 // [B][SSH][D]
  float* xstart = wsU + half_elems;                 // [B][SS][D] (absolute)
  float* xcarry = xstart + (size_t)BB * SS * DD;    // [B][D]

  for (int h = 0; h < 2; ++h) {
    const int s_base = h * SSH;
    const float* xin = (h == 0) ? x0 : xcarry;
    seg_reduce<<<BB * SSH, 256, 0, stream>>>(a, u, wsA, wsU, s_base);
    seg_scan<<<BB * (DD / 64), 256, 0, stream>>>(xin, wsA, wsU, xstart,
                                                 xcarry, s_base);
    seg_apply<<<BB * SSH, 256, 0, stream>>>(a, u, xstart, out, s_base);
  }
}